// Round 5
// baseline (125.465 us; speedup 1.0000x reference)
//
#include <hip/hip_runtime.h>
#include <hip/hip_bf16.h>

// LDConv (deformable sampling + (N,1) conv + BN + SiLU) for MI355X.
//
// Round-18 = R15 (proven 109us k_fused) with DOUBLED pixel tile: 64 px /
// block, 8 waves (512 thr), grid 800.
//  - R14/R16/R17 post-mortem: three scheduling-level changes all neutral
//    (MfmaUtil pinned at 16%, dur 109-117us). Latency-exposure theory is
//    DEAD. Byte-count re-derivation: wf weight streams are 64 KB per
//    block-step -> 921 MB of L2 traffic; total L2 ~2.1 GB in ~100us
//    ~= 21 TB/s ~= 60% of the 34.5 TB/s ceiling -> the kernel is
//    L1<->L2 BANDWIDTH-bound. Schedules can't fix bytes.
//  - Fix: weight reuse scales with px/block. 64 px halves wf (921->460MB)
//    and wpf (460->230MB) traffic; total L2 bytes -33%. Per-wave code is
//    byte-identical R15 (proven schedule); geometry only: pw = wave's
//    px-half, A_lds 64 rows (32KB dbuf), Btile 64 rows, descL 576.
//  - LDS 48KB -> 2 blocks/CU @ launch_bounds(512,4) (128 VGPR cap, same
//    proven budget); 16 waves/CU potential (vs 10.4 measured) adds TLP.
//  - Spill tripwire: WRITE_SIZE must stay ~51 MB.
// Carried: fused phase-1 offset conv -> descL in LDS, XCD swizzle (800%8==0),
// XOR-swizzled A_lds, BN scale folded into wf, fast SiLU, setprio.

typedef __attribute__((ext_vector_type(8))) short bf16x8;
typedef __attribute__((ext_vector_type(4))) float f32x4;
typedef __attribute__((ext_vector_type(2))) float f32x2;
typedef __attribute__((ext_vector_type(4))) unsigned int u32x4;

#define NHW 6400
#define NPIX 80

__device__ __forceinline__ unsigned short f2bf(float f){
  __hip_bfloat16 h = __float2bfloat16(f);
  unsigned short u; __builtin_memcpy(&u, &h, 2); return u;
}
__device__ __forceinline__ f32x2 bfp2f(unsigned int u){
  union { unsigned int i; float f; } a, b;
  a.i = u << 16; b.i = u & 0xffff0000u;
  f32x2 r; r.x = a.f; r.y = b.f; return r;
}
__device__ __forceinline__ unsigned pk_bf16(float a, float b){
  unsigned r;
  asm("v_cvt_pk_bf16_f32 %0, %1, %2" : "=v"(r) : "v"(a), "v"(b));
  return r;
}
__device__ __forceinline__ void splitbf(float v, unsigned short& hi, unsigned short& lo){
  hi = f2bf(v);
  union { unsigned int i; float f; } h; h.i = (unsigned)hi << 16;
  lo = f2bf(v - h.f);
}
__device__ __forceinline__ float f16u2f(unsigned int u){
  unsigned short s = (unsigned short)u; _Float16 h;
  __builtin_memcpy(&h, &s, 2); return (float)h;
}
__device__ __forceinline__ unsigned short f2f16u(float f){
  _Float16 h = (_Float16)f; unsigned short s;
  __builtin_memcpy(&s, &h, 2); return s;
}
__device__ __forceinline__ float fast_silu(float v){
  float e, r;
  asm("v_exp_f32 %0, %1" : "=v"(e) : "v"(v * -1.44269504088896f)); // exp(-v)
  asm("v_rcp_f32 %0, %1" : "=v"(r) : "v"(1.0f + e));
  return v * r;
}

// ---------------- merged: transpose (blk<800) + weight prep ----------------
__global__ __launch_bounds__(256) void k_pre(const float* __restrict__ x,
                                             const float* __restrict__ w_conv,
                                             const float* __restrict__ w_pconv,
                                             const float* __restrict__ gamma,
                                             const float* __restrict__ beta,
                                             const float* __restrict__ mean,
                                             const float* __restrict__ var,
                                             unsigned short* __restrict__ xt,
                                             unsigned short* __restrict__ xtl,
                                             uint4* __restrict__ wf,
                                             uint4* __restrict__ wpfH,
                                             uint4* __restrict__ wpfL,
                                             float* __restrict__ shift){
  __shared__ unsigned short tileH[64 * 132];
  __shared__ unsigned short tileL[64 * 132];
  int blk = blockIdx.x; int t = threadIdx.x;
  if (blk < 800){
    int b = blk / 100; int pixbase = (blk % 100) * 64;
    int lane = t & 63; int cg = t >> 6;
    for (int ci = 0; ci < 32; ++ci){
      int c = cg * 32 + ci;
      float v = x[(b * 128 + c) * NHW + pixbase + lane];
      unsigned short hi, lo; splitbf(v, hi, lo);
      tileH[lane * 132 + c] = hi;
      tileL[lane * 132 + c] = lo;
    }
    __syncthreads();
    for (int i = 0; i < 8; ++i){
      int slot = t + i * 256; int m = slot >> 5; int c = (slot & 31) * 4;
      uint2 vH = *reinterpret_cast<const uint2*>(&tileH[m * 132 + c]);
      uint2 vL = *reinterpret_cast<const uint2*>(&tileL[m * 132 + c]);
      *reinterpret_cast<uint2*>(xt  + (b * NHW + pixbase + m) * 128 + c) = vH;
      *reinterpret_cast<uint2*>(xtl + (b * NHW + pixbase + m) * 128 + c) = vL;
    }
    return;
  }
  int pblk = blk - 800;
  if (pblk < 144){
    int id = pblk * 256 + t;
    int lane = id & 63, ofrag = (id >> 6) & 15, kc = (id >> 10) & 3, n = id >> 12;
    int o = ofrag * 16 + (lane & 15), cb = kc * 32 + ((lane >> 4) & 3) * 8;
    float sc = gamma[o] * rsqrtf(var[o] + 1e-5f);       // BN scale folded in
    unsigned short h[8];
    for (int j = 0; j < 8; ++j) h[j] = f2bf(w_conv[(o * 128 + cb + j) * 9 + n] * sc);
    uint4 v;
    v.x = (unsigned)h[0] | ((unsigned)h[1] << 16);
    v.y = (unsigned)h[2] | ((unsigned)h[3] << 16);
    v.z = (unsigned)h[4] | ((unsigned)h[5] << 16);
    v.w = (unsigned)h[6] | ((unsigned)h[7] << 16);
    wf[id] = v;
  } else if (pblk < 180){
    int isLo = (pblk >= 162);
    int id = (pblk - (isLo ? 162 : 144)) * 256 + t;
    int lane = id & 63, ofrag = (id >> 6) & 1, kc = (id >> 7) & 3, tap = id >> 9;
    int o = ofrag * 16 + (lane & 15), cb = kc * 32 + ((lane >> 4) & 3) * 8;
    unsigned short h[8];
    for (int j = 0; j < 8; ++j){
      unsigned short hi = 0, lo = 0;
      if (o < 18) splitbf(w_pconv[(o * 128 + cb + j) * 9 + tap], hi, lo);
      h[j] = isLo ? lo : hi;
    }
    uint4 v;
    v.x = (unsigned)h[0] | ((unsigned)h[1] << 16);
    v.y = (unsigned)h[2] | ((unsigned)h[3] << 16);
    v.z = (unsigned)h[4] | ((unsigned)h[5] << 16);
    v.w = (unsigned)h[6] | ((unsigned)h[7] << 16);
    if (isLo) wpfL[id] = v; else wpfH[id] = v;
  } else {
    float sc = gamma[t] * rsqrtf(var[t] + 1e-5f);
    shift[t] = beta[t] - mean[t] * sc;
  }
}

// ---------------- fused 64-px: offset conv -> descL (LDS) -> gather GEMM ----------------
// 512 threads = 8 waves. Phase 1: og = wv&1 (o-frag), pf = wv>>1 (px quarter).
// Phase 2: ow = wv&3 (64-oc slice), pw = wv>>2 (32-px half).
// LDS map (49152 B): [0,34816) BtileH/L (phase 1) / [0,32768) A_lds[2]
// (phase 2) | [34816,39936) off_lds | [39936,49152) descL (persistent).
__global__ __launch_bounds__(512, 4) void k_fused(const unsigned short* __restrict__ xt,
                                                  const unsigned short* __restrict__ xtl,
                                                  const uint4* __restrict__ wpfH,
                                                  const uint4* __restrict__ wpfL,
                                                  const float* __restrict__ bpc,
                                                  const float* __restrict__ pn,
                                                  const uint4* __restrict__ wf,
                                                  const float* __restrict__ shift,
                                                  float* __restrict__ out){
  int bid = blockIdx.x;
  int blk = (bid & 7) * 100 + (bid >> 3);          // XCD swizzle (800 % 8 == 0)
  int b = blk / 100; int pixbase = (blk % 100) * 64;
  int t = threadIdx.x; int lane = t & 63;

  __shared__ alignas(16) char smem[49152];
  short* BtileH  = (short*)(smem);                 // 64*136*2 = 17408 B
  short* BtileL  = (short*)(smem + 17408);         // 17408 B
  float* off_lds = (float*)(smem + 34816);         // 64*20*4 = 5120 B
  uint4* descL   = (uint4*)(smem + 39936);         // 9*64*16 = 9216 B

  // ======================= phase 1: offset conv =======================
  {
    int wv = t >> 6; int og = wv & 1; int pf = wv >> 1;      // pf 0..3
    f32x4 acc = (f32x4){0.f, 0.f, 0.f, 0.f};
    const unsigned short* xbH = xt  + (size_t)b * NHW * 128;
    const unsigned short* xbL = xtl + (size_t)b * NHW * 128;

    int m_i[4], c_i[4], h_i[4], w_i[4];
#pragma unroll
    for (int i = 0; i < 4; ++i){
      int slot = t + i * 512;                                // 2048 slots
      m_i[i] = slot >> 5; c_i[i] = (slot & 31) * 4;          // 64 rows
      int p = pixbase + m_i[i];
      h_i[i] = p / NPIX; w_i[i] = p % NPIX;
    }

    uint2 rH[4], rL[4];

#define LOADTAP(DH, DW)                                                        \
  _Pragma("unroll")                                                            \
  for (int i = 0; i < 4; ++i){                                                 \
    int h2 = h_i[i] + (DH), w2 = w_i[i] + (DW);                                \
    uint2 vH; vH.x = 0u; vH.y = 0u;                                            \
    uint2 vL; vL.x = 0u; vL.y = 0u;                                            \
    if ((unsigned)h2 < NPIX && (unsigned)w2 < NPIX){                           \
      int off = (h2 * NPIX + w2) * 128 + c_i[i];                               \
      vH = *reinterpret_cast<const uint2*>(xbH + off);                         \
      vL = *reinterpret_cast<const uint2*>(xbL + off);                         \
    }                                                                          \
    rH[i] = vH; rL[i] = vL;                                                    \
  }

#define WRITETILE()                                                            \
  _Pragma("unroll")                                                            \
  for (int i = 0; i < 4; ++i){                                                 \
    *reinterpret_cast<uint2*>(&BtileH[m_i[i] * 136 + c_i[i]]) = rH[i];         \
    *reinterpret_cast<uint2*>(&BtileL[m_i[i] * 136 + c_i[i]]) = rL[i];         \
  }

    LOADTAP(-1, -1)
    WRITETILE()
    __syncthreads();

#pragma unroll 1
    for (int tap = 0; tap < 9; ++tap){
      if (tap < 8){
        int dh2 = (tap + 1) / 3 - 1, dw2 = (tap + 1) % 3 - 1;
        LOADTAP(dh2, dw2)
      }
#pragma unroll
      for (int kc = 0; kc < 4; ++kc){
        int boff = (pf * 16 + (lane & 15)) * 136 + kc * 32 + ((lane >> 4) & 3) * 8;
        bf16x8 bH = *reinterpret_cast<const bf16x8*>(&BtileH[boff]);
        bf16x8 bL = *reinterpret_cast<const bf16x8*>(&BtileL[boff]);
        int widx = ((tap * 4 + kc) * 2 + og) * 64 + lane;
        bf16x8 aH = *reinterpret_cast<const bf16x8*>(&wpfH[widx]);
        bf16x8 aL = *reinterpret_cast<const bf16x8*>(&wpfL[widx]);
        acc = __builtin_amdgcn_mfma_f32_16x16x32_bf16(aH, bH, acc, 0, 0, 0);
        acc = __builtin_amdgcn_mfma_f32_16x16x32_bf16(aH, bL, acc, 0, 0, 0);
        acc = __builtin_amdgcn_mfma_f32_16x16x32_bf16(aL, bH, acc, 0, 0, 0);
        acc = __builtin_amdgcn_mfma_f32_16x16x32_bf16(aL, bL, acc, 0, 0, 0);
      }
      __syncthreads();
      if (tap < 8){
        WRITETILE()
        __syncthreads();
      }
    }

    int pl = pf * 16 + (lane & 15);                          // 0..63
#pragma unroll
    for (int r = 0; r < 4; ++r){
      int o = og * 16 + ((lane >> 4) & 3) * 4 + r;
      if (o < 18) off_lds[pl * 20 + o] = acc[r] + bpc[o];
    }
    __syncthreads();

    for (int item = t; item < 576; item += 512){
      int m = item / 9, n = item % 9;
      int p = pixbase + m; int h = p / NPIX, w = p % NPIX;
      float px = (float)h + pn[n]     + off_lds[m * 20 + n];
      float py = (float)w + pn[9 + n] + off_lds[m * 20 + 9 + n];
      float flx = floorf(px), fly = floorf(py);
      float qltx = fminf(fmaxf(flx, 0.f), 79.f);
      float qrbx = fminf(fmaxf(flx + 1.f, 0.f), 79.f);
      float qlty = fminf(fmaxf(fly, 0.f), 79.f);
      float qrby = fminf(fmaxf(fly + 1.f, 0.f), 79.f);
      float pcx = fminf(fmaxf(px, 0.f), 79.f);
      float pcy = fminf(fmaxf(py, 0.f), 79.f);
      float dxl = 1.f + (qltx - pcx), dxr = 1.f - (qrbx - pcx);
      float dyl = 1.f + (qlty - pcy), dyr = 1.f - (qrby - pcy);
      unsigned ix_l = (unsigned)(int)qltx, ix_r = (unsigned)(int)qrbx;
      unsigned iy_l = (unsigned)(int)qlty, iy_r = (unsigned)(int)qrby;
      uint4 d;
      d.x = (ix_l * NPIX + iy_l) | ((ix_r * NPIX + iy_r) << 16);
      d.y = (ix_l * NPIX + iy_r) | ((ix_r * NPIX + iy_l) << 16);
      d.z = (unsigned)f2f16u(dxl * dyl) | ((unsigned)f2f16u(dxr * dyr) << 16);
      d.w = (unsigned)f2f16u(dxl * dyr) | ((unsigned)f2f16u(dxr * dyl) << 16);
      descL[n * 64 + m] = d;
    }
#undef LOADTAP
#undef WRITETILE
  }
  __syncthreads();                 // descL visible; Btile region dead
  __builtin_amdgcn_sched_barrier(0);

  // ======================= phase 2: gather GEMM (R15 schedule) =======================
  {
    int wv = t >> 6;
    int ow = wv & 3;                     // 64-oc slice
    int pw = wv >> 2;                    // 32-px half
    char* A_lds0 = smem;                 // A_lds[buf] = smem + buf*16384
    const char* xb = (const char*)(xt + (size_t)b * NHW * 128);

    int m0 = t >> 4;            // row 0..31
    int m1 = m0 + 32;           // row 32..63
    int cb = (t & 15) * 16;     // byte col 0..240
    int ls0 = m0 * 256 + (cb ^ ((m0 & 7) << 4));
    int ls1 = m1 * 256 + (cb ^ ((m1 & 7) << 4));

    f32x4 acc[4][2];
#pragma unroll
    for (int of = 0; of < 4; ++of)
#pragma unroll
      for (int pf = 0; pf < 2; ++pf)
        acc[of][pf] = (f32x4){0.f, 0.f, 0.f, 0.f};

    u32x4 GX[4], GY[4];          // serialized liveness (never both live)
    uint2 zwX, zwY;
    uint4 dB0, dB1;

#define DLD(N, M) descL[(N) * 64 + (M)]

#define ISSUE_X()                                                              \
  {                                                                            \
    zwX.x = dB0.z; zwX.y = dB0.w;                                              \
    GX[0] = *reinterpret_cast<const u32x4*>(xb + (dB0.x & 0xffffu) * 256u + (unsigned)cb); \
    GX[1] = *reinterpret_cast<const u32x4*>(xb + (dB0.x >> 16)     * 256u + (unsigned)cb); \
    GX[2] = *reinterpret_cast<const u32x4*>(xb + (dB0.y & 0xffffu) * 256u + (unsigned)cb); \
    GX[3] = *reinterpret_cast<const u32x4*>(xb + (dB0.y >> 16)     * 256u + (unsigned)cb); \
  }

#define ISSUE_Y()                                                              \
  {                                                                            \
    zwY.x = dB1.z; zwY.y = dB1.w;                                              \
    GY[0] = *reinterpret_cast<const u32x4*>(xb + (dB1.x & 0xffffu) * 256u + (unsigned)cb); \
    GY[1] = *reinterpret_cast<const u32x4*>(xb + (dB1.x >> 16)     * 256u + (unsigned)cb); \
    GY[2] = *reinterpret_cast<const u32x4*>(xb + (dB1.y & 0xffffu) * 256u + (unsigned)cb); \
    GY[3] = *reinterpret_cast<const u32x4*>(xb + (dB1.y >> 16)     * 256u + (unsigned)cb); \
  }

#define COMB(G, ZW, LSO, WB)                                                   \
  {                                                                            \
    float w0 = f16u2f(ZW.x & 0xffffu), w1 = f16u2f(ZW.x >> 16);                \
    float w2 = f16u2f(ZW.y & 0xffffu), w3 = f16u2f(ZW.y >> 16);                \
    u32x4 pk;                                                                  \
    _Pragma("unroll")                                                          \
    for (int j = 0; j < 4; ++j){                                               \
      f32x2 a = w0 * bfp2f(G[0][j]) + w1 * bfp2f(G[1][j])                      \
              + w2 * bfp2f(G[2][j]) + w3 * bfp2f(G[3][j]);                     \
      pk[j] = pk_bf16(a.x, a.y);                                               \
    }                                                                          \
    *reinterpret_cast<u32x4*>((WB) + (LSO)) = pk;                              \
  }

#define MFMA_HALF(NN, KCA, KCB)                                                \
  {                                                                            \
    const char* ab = A_lds0 + ((NN) & 1) * 16384;                              \
    __builtin_amdgcn_s_setprio(1);                                             \
    _Pragma("unroll")                                                          \
    for (int kc = (KCA); kc <= (KCB); ++kc){                                   \
      bf16x8 bfrk[2];                                                          \
      _Pragma("unroll")                                                        \
      for (int pf = 0; pf < 2; ++pf){                                          \
        int row = pw * 32 + pf * 16 + (lane & 15);                             \
        bfrk[pf] = *reinterpret_cast<const bf16x8*>(                           \
            ab + row * 256 + ((kc * 64 + ((lane >> 4) & 3) * 16) ^ ((row & 7) << 4))); \
      }                                                                        \
      _Pragma("unroll")                                                        \
      for (int of = 0; of < 4; ++of){                                          \
        bf16x8 afr = *reinterpret_cast<const bf16x8*>(                         \
            &wf[((((NN) * 4 + kc) * 16) + ow * 4 + of) * 64 + lane]);          \
        _Pragma("unroll")                                                      \
        for (int pf = 0; pf < 2; ++pf)                                         \
          acc[of][pf] = __builtin_amdgcn_mfma_f32_16x16x32_bf16(afr, bfrk[pf], acc[of][pf], 0, 0, 0); \
      }                                                                        \
    }                                                                          \
    __builtin_amdgcn_s_setprio(0);                                             \
  }

// STEP(NN): issue X(data NN+1) | descL0(NN+2) | MFMA kc0-1 | COMB_X (GX dies)
//           | [sched fence] | issue Y(NN+1) | descL1(NN+2) | MFMA kc2-3
//           | COMB_Y | barrier.   (R15's proven schedule, 64-px geometry)
#define STEP(NN)                                                               \
  {                                                                            \
    if ((NN) < 8){ ISSUE_X() }                                                 \
    if ((NN) < 7){ dB0 = DLD((NN) + 2, m0); }                                  \
    MFMA_HALF(NN, 0, 1)                                                        \
    if ((NN) < 8){                                                             \
      COMB(GX, zwX, ls0, A_lds0 + (((NN) + 1) & 1) * 16384)                    \
      __builtin_amdgcn_sched_barrier(0);                                       \
      ISSUE_Y()                                                                \
    }                                                                          \
    if ((NN) < 7){ dB1 = DLD((NN) + 2, m1); }                                  \
    MFMA_HALF(NN, 2, 3)                                                        \
    if ((NN) < 8){                                                             \
      COMB(GY, zwY, ls1, A_lds0 + (((NN) + 1) & 1) * 16384)                    \
    }                                                                          \
    __syncthreads();                                                           \
  }

    // prologue: data 0 -> buf0, one gather set live at a time
    dB0 = DLD(0, m0); dB1 = DLD(0, m1);
    ISSUE_X()
    COMB(GX, zwX, ls0, A_lds0)
    __builtin_amdgcn_sched_barrier(0);
    ISSUE_Y()
    COMB(GY, zwY, ls1, A_lds0)
    dB0 = DLD(1, m0); dB1 = DLD(1, m1);
    __syncthreads();

    STEP(0) STEP(1) STEP(2) STEP(3) STEP(4) STEP(5) STEP(6) STEP(7) STEP(8)

    // epilogue: +shift, fast SiLU, store
#pragma unroll
    for (int of = 0; of < 4; ++of)
#pragma unroll
      for (int pf = 0; pf < 2; ++pf){
        int pix = pixbase + pw * 32 + pf * 16 + (lane & 15);
#pragma unroll
        for (int r = 0; r < 4; ++r){
          int o = ow * 64 + of * 16 + ((lane >> 4) & 3) * 4 + r;
          float v = acc[of][pf][r] + shift[o];
          out[(size_t)(b * 256 + o) * NHW + pix] = fast_silu(v);
        }
      }
#undef DLD
#undef ISSUE_X
#undef ISSUE_Y
#undef COMB
#undef MFMA_HALF
#undef STEP
  }
}

extern "C" void kernel_launch(void* const* d_in, const int* in_sizes, int n_in,
                              void* d_out, int out_size, void* d_ws, size_t ws_size,
                              hipStream_t stream){
  const float* x       = (const float*)d_in[0];
  const float* w_pconv = (const float*)d_in[1];
  const float* b_pconv = (const float*)d_in[2];
  const float* w_conv  = (const float*)d_in[3];
  const float* gamma   = (const float*)d_in[4];
  const float* beta    = (const float*)d_in[5];
  const float* mean    = (const float*)d_in[6];
  const float* var     = (const float*)d_in[7];
  const float* pn      = (const float*)d_in[8];

  char* ws = (char*)d_ws;
  unsigned short* xt  = (unsigned short*)(ws + 0);           // 13,107,200 B
  unsigned short* xtl = (unsigned short*)(ws + 13107200);    // 13,107,200 B
  // (desc region [26214400, 33587200) unused — kept for layout stability)
  uint4* wf           = (uint4*)(ws + 33587200);             //    589,824 B
  uint4* wpfH         = (uint4*)(ws + 34177024);             //     73,728 B
  uint4* wpfL         = (uint4*)(ws + 34250752);             //     73,728 B
  float* shift        = (float*)(ws + 34324480);             //      1,024 B
  float* out          = (float*)d_out;

  k_pre<<<981, 256, 0, stream>>>(x, w_conv, w_pconv, gamma, beta, mean, var,
                                 xt, xtl, wf, wpfH, wpfL, shift);
  k_fused<<<800, 512, 0, stream>>>(xt, xtl, wpfH, wpfL, b_pconv, pn, wf, shift, out);
}

// Round 6
// 114.686 us; speedup vs baseline: 1.0940x; 1.0940x over previous
//
#include <hip/hip_runtime.h>
#include <hip/hip_bf16.h>

// LDConv (deformable sampling + (N,1) conv + BN + SiLU) for MI355X.
//
// Round-19 = R15 VERBATIM (proven best: 109us k_fused / 114.6 total;
// R18's 64-px tile reverted: halving wf L2 traffic made it WORSE ->
// bandwidth theory dead) + ONE change: non-draining barriers.
//  - Mechanism: hipcc emits `s_waitcnt vmcnt(0) lgkmcnt(0)` before every
//    s_barrier (__syncthreads drains the whole VMEM queue). Phase 2 has 10
//    barriers, phase 1 has 19; each drain costs a loaded-L2 round trip
//    (~300-500cy) because MFMA's streaming wf loads are issued ~50cy before
//    the barrier. ~29 barriers x ~400cy ~= 12k cy/block serial — matches
//    the unexplained per-round gap. This is why R14/R16/R17/R18 (schedule,
//    tile, traffic) were ALL neutral: every pipeline was nullified at the
//    next __syncthreads.
//  - Fix (T3/T4 pattern, +38-73% measured on 8-phase GEMM in learn_hip):
//    replace in-loop __syncthreads with `s_waitcnt lgkmcnt(0); s_barrier`
//    (inline asm). LDS cross-wave hazards are fully ordered by lgkmcnt(0)
//    + barrier (each wave's ds ops retire at its own lgkmcnt(0); VMEM
//    loads land in private registers -> no cross-wave hazard; compiler
//    still inserts counted vmcnt before each load's use). Gathers and wf
//    streams now stay in flight ACROSS barriers.
//  - Kept plain __syncthreads at off_lds exchange + phase transition.
// Carried: fused phase-1 offset conv -> descL in LDS, XCD swizzle,
// XOR-swizzled 16KB dbuf A_lds, BN folded into wf, fast SiLU, setprio,
// launch_bounds(256,4).

typedef __attribute__((ext_vector_type(8))) short bf16x8;
typedef __attribute__((ext_vector_type(4))) float f32x4;
typedef __attribute__((ext_vector_type(2))) float f32x2;
typedef __attribute__((ext_vector_type(4))) unsigned int u32x4;

#define NHW 6400
#define NPIX 80

// non-draining barrier: orders all LDS ops (lgkmcnt) but leaves VMEM loads
// in flight (no vmcnt drain). "memory" clobber pins IR-level mem ordering.
#define SOFT_BARRIER() asm volatile("s_waitcnt lgkmcnt(0)\n\ts_barrier" ::: "memory")

__device__ __forceinline__ unsigned short f2bf(float f){
  __hip_bfloat16 h = __float2bfloat16(f);
  unsigned short u; __builtin_memcpy(&u, &h, 2); return u;
}
__device__ __forceinline__ f32x2 bfp2f(unsigned int u){
  union { unsigned int i; float f; } a, b;
  a.i = u << 16; b.i = u & 0xffff0000u;
  f32x2 r; r.x = a.f; r.y = b.f; return r;
}
__device__ __forceinline__ unsigned pk_bf16(float a, float b){
  unsigned r;
  asm("v_cvt_pk_bf16_f32 %0, %1, %2" : "=v"(r) : "v"(a), "v"(b));
  return r;
}
__device__ __forceinline__ void splitbf(float v, unsigned short& hi, unsigned short& lo){
  hi = f2bf(v);
  union { unsigned int i; float f; } h; h.i = (unsigned)hi << 16;
  lo = f2bf(v - h.f);
}
__device__ __forceinline__ float f16u2f(unsigned int u){
  unsigned short s = (unsigned short)u; _Float16 h;
  __builtin_memcpy(&h, &s, 2); return (float)h;
}
__device__ __forceinline__ unsigned short f2f16u(float f){
  _Float16 h = (_Float16)f; unsigned short s;
  __builtin_memcpy(&s, &h, 2); return s;
}
__device__ __forceinline__ float fast_silu(float v){
  float e, r;
  asm("v_exp_f32 %0, %1" : "=v"(e) : "v"(v * -1.44269504088896f)); // exp(-v)
  asm("v_rcp_f32 %0, %1" : "=v"(r) : "v"(1.0f + e));
  return v * r;
}

// ---------------- merged: transpose (blk<800) + weight prep ----------------
__global__ __launch_bounds__(256) void k_pre(const float* __restrict__ x,
                                             const float* __restrict__ w_conv,
                                             const float* __restrict__ w_pconv,
                                             const float* __restrict__ gamma,
                                             const float* __restrict__ beta,
                                             const float* __restrict__ mean,
                                             const float* __restrict__ var,
                                             unsigned short* __restrict__ xt,
                                             unsigned short* __restrict__ xtl,
                                             uint4* __restrict__ wf,
                                             uint4* __restrict__ wpfH,
                                             uint4* __restrict__ wpfL,
                                             float* __restrict__ shift){
  __shared__ unsigned short tileH[64 * 132];
  __shared__ unsigned short tileL[64 * 132];
  int blk = blockIdx.x; int t = threadIdx.x;
  if (blk < 800){
    int b = blk / 100; int pixbase = (blk % 100) * 64;
    int lane = t & 63; int cg = t >> 6;
    for (int ci = 0; ci < 32; ++ci){
      int c = cg * 32 + ci;
      float v = x[(b * 128 + c) * NHW + pixbase + lane];
      unsigned short hi, lo; splitbf(v, hi, lo);
      tileH[lane * 132 + c] = hi;
      tileL[lane * 132 + c] = lo;
    }
    __syncthreads();
    for (int i = 0; i < 8; ++i){
      int slot = t + i * 256; int m = slot >> 5; int c = (slot & 31) * 4;
      uint2 vH = *reinterpret_cast<const uint2*>(&tileH[m * 132 + c]);
      uint2 vL = *reinterpret_cast<const uint2*>(&tileL[m * 132 + c]);
      *reinterpret_cast<uint2*>(xt  + (b * NHW + pixbase + m) * 128 + c) = vH;
      *reinterpret_cast<uint2*>(xtl + (b * NHW + pixbase + m) * 128 + c) = vL;
    }
    return;
  }
  int pblk = blk - 800;
  if (pblk < 144){
    int id = pblk * 256 + t;
    int lane = id & 63, ofrag = (id >> 6) & 15, kc = (id >> 10) & 3, n = id >> 12;
    int o = ofrag * 16 + (lane & 15), cb = kc * 32 + ((lane >> 4) & 3) * 8;
    float sc = gamma[o] * rsqrtf(var[o] + 1e-5f);       // BN scale folded in
    unsigned short h[8];
    for (int j = 0; j < 8; ++j) h[j] = f2bf(w_conv[(o * 128 + cb + j) * 9 + n] * sc);
    uint4 v;
    v.x = (unsigned)h[0] | ((unsigned)h[1] << 16);
    v.y = (unsigned)h[2] | ((unsigned)h[3] << 16);
    v.z = (unsigned)h[4] | ((unsigned)h[5] << 16);
    v.w = (unsigned)h[6] | ((unsigned)h[7] << 16);
    wf[id] = v;
  } else if (pblk < 180){
    int isLo = (pblk >= 162);
    int id = (pblk - (isLo ? 162 : 144)) * 256 + t;
    int lane = id & 63, ofrag = (id >> 6) & 1, kc = (id >> 7) & 3, tap = id >> 9;
    int o = ofrag * 16 + (lane & 15), cb = kc * 32 + ((lane >> 4) & 3) * 8;
    unsigned short h[8];
    for (int j = 0; j < 8; ++j){
      unsigned short hi = 0, lo = 0;
      if (o < 18) splitbf(w_pconv[(o * 128 + cb + j) * 9 + tap], hi, lo);
      h[j] = isLo ? lo : hi;
    }
    uint4 v;
    v.x = (unsigned)h[0] | ((unsigned)h[1] << 16);
    v.y = (unsigned)h[2] | ((unsigned)h[3] << 16);
    v.z = (unsigned)h[4] | ((unsigned)h[5] << 16);
    v.w = (unsigned)h[6] | ((unsigned)h[7] << 16);
    if (isLo) wpfL[id] = v; else wpfH[id] = v;
  } else {
    float sc = gamma[t] * rsqrtf(var[t] + 1e-5f);
    shift[t] = beta[t] - mean[t] * sc;
  }
}

// ---------------- fused: offset conv -> descL (LDS) -> gather GEMM + BN + SiLU ----------------
// LDS map (24576 B): [0,17408) BtileH/L  | [17408,19968) off_lds
//                    [0,16384)  A_lds[2] (phase 2, after barrier)
//                    [19968,24576) descL (persists across phases)
__global__ __launch_bounds__(256, 4) void k_fused(const unsigned short* __restrict__ xt,
                                                  const unsigned short* __restrict__ xtl,
                                                  const uint4* __restrict__ wpfH,
                                                  const uint4* __restrict__ wpfL,
                                                  const float* __restrict__ bpc,
                                                  const float* __restrict__ pn,
                                                  const uint4* __restrict__ wf,
                                                  const float* __restrict__ shift,
                                                  float* __restrict__ out){
  int bid = blockIdx.x;
  int blk = (bid & 7) * 200 + (bid >> 3);          // XCD swizzle (1600 % 8 == 0)
  int b = blk / 200; int pixbase = (blk % 200) * 32;
  int t = threadIdx.x; int lane = t & 63;

  __shared__ alignas(16) char smem[24576];
  short* BtileH  = (short*)(smem);                 // 32*136*2 = 8704 B
  short* BtileL  = (short*)(smem + 8704);          // 8704 B
  float* off_lds = (float*)(smem + 17408);         // 32*20*4 = 2560 B
  uint4* descL   = (uint4*)(smem + 19968);         // 9*32*16 = 4608 B

  // ======================= phase 1: offset conv =======================
  {
    int wv = t >> 6; int og = wv & 1; int pf = wv >> 1;
    f32x4 acc = (f32x4){0.f, 0.f, 0.f, 0.f};
    const unsigned short* xbH = xt  + (size_t)b * NHW * 128;
    const unsigned short* xbL = xtl + (size_t)b * NHW * 128;

    int m_i[4], c_i[4], h_i[4], w_i[4];
#pragma unroll
    for (int i = 0; i < 4; ++i){
      int slot = t + i * 256;
      m_i[i] = slot >> 5; c_i[i] = (slot & 31) * 4;
      int p = pixbase + m_i[i];
      h_i[i] = p / NPIX; w_i[i] = p % NPIX;
    }

    uint2 rH[4], rL[4];

#define LOADTAP(DH, DW)                                                        \
  _Pragma("unroll")                                                            \
  for (int i = 0; i < 4; ++i){                                                 \
    int h2 = h_i[i] + (DH), w2 = w_i[i] + (DW);                                \
    uint2 vH; vH.x = 0u; vH.y = 0u;                                            \
    uint2 vL; vL.x = 0u; vL.y = 0u;                                            \
    if ((unsigned)h2 < NPIX && (unsigned)w2 < NPIX){                           \
      int off = (h2 * NPIX + w2) * 128 + c_i[i];                               \
      vH = *reinterpret_cast<const uint2*>(xbH + off);                         \
      vL = *reinterpret_cast<const uint2*>(xbL + off);                         \
    }                                                                          \
    rH[i] = vH; rL[i] = vL;                                                    \
  }

#define WRITETILE()                                                            \
  _Pragma("unroll")                                                            \
  for (int i = 0; i < 4; ++i){                                                 \
    *reinterpret_cast<uint2*>(&BtileH[m_i[i] * 136 + c_i[i]]) = rH[i];         \
    *reinterpret_cast<uint2*>(&BtileL[m_i[i] * 136 + c_i[i]]) = rL[i];         \
  }

    LOADTAP(-1, -1)
    WRITETILE()
    SOFT_BARRIER();

#pragma unroll 1
    for (int tap = 0; tap < 9; ++tap){
      if (tap < 8){
        int dh2 = (tap + 1) / 3 - 1, dw2 = (tap + 1) % 3 - 1;
        LOADTAP(dh2, dw2)
      }
#pragma unroll
      for (int kc = 0; kc < 4; ++kc){
        int boff = (pf * 16 + (lane & 15)) * 136 + kc * 32 + ((lane >> 4) & 3) * 8;
        bf16x8 bH = *reinterpret_cast<const bf16x8*>(&BtileH[boff]);
        bf16x8 bL = *reinterpret_cast<const bf16x8*>(&BtileL[boff]);
        int widx = ((tap * 4 + kc) * 2 + og) * 64 + lane;
        bf16x8 aH = *reinterpret_cast<const bf16x8*>(&wpfH[widx]);
        bf16x8 aL = *reinterpret_cast<const bf16x8*>(&wpfL[widx]);
        acc = __builtin_amdgcn_mfma_f32_16x16x32_bf16(aH, bH, acc, 0, 0, 0);
        acc = __builtin_amdgcn_mfma_f32_16x16x32_bf16(aH, bL, acc, 0, 0, 0);
        acc = __builtin_amdgcn_mfma_f32_16x16x32_bf16(aL, bH, acc, 0, 0, 0);
        acc = __builtin_amdgcn_mfma_f32_16x16x32_bf16(aL, bL, acc, 0, 0, 0);
      }
      SOFT_BARRIER();
      if (tap < 8){
        WRITETILE()
        SOFT_BARRIER();
      }
    }

    int pl = pf * 16 + (lane & 15);
#pragma unroll
    for (int r = 0; r < 4; ++r){
      int o = og * 16 + ((lane >> 4) & 3) * 4 + r;
      if (o < 18) off_lds[pl * 20 + o] = acc[r] + bpc[o];
    }
    __syncthreads();

    for (int item = t; item < 288; item += 256){
      int m = item / 9, n = item % 9;
      int p = pixbase + m; int h = p / NPIX, w = p % NPIX;
      float px = (float)h + pn[n]     + off_lds[m * 20 + n];
      float py = (float)w + pn[9 + n] + off_lds[m * 20 + 9 + n];
      float flx = floorf(px), fly = floorf(py);
      float qltx = fminf(fmaxf(flx, 0.f), 79.f);
      float qrbx = fminf(fmaxf(flx + 1.f, 0.f), 79.f);
      float qlty = fminf(fmaxf(fly, 0.f), 79.f);
      float qrby = fminf(fmaxf(fly + 1.f, 0.f), 79.f);
      float pcx = fminf(fmaxf(px, 0.f), 79.f);
      float pcy = fminf(fmaxf(py, 0.f), 79.f);
      float dxl = 1.f + (qltx - pcx), dxr = 1.f - (qrbx - pcx);
      float dyl = 1.f + (qlty - pcy), dyr = 1.f - (qrby - pcy);
      unsigned ix_l = (unsigned)(int)qltx, ix_r = (unsigned)(int)qrbx;
      unsigned iy_l = (unsigned)(int)qlty, iy_r = (unsigned)(int)qrby;
      uint4 d;
      d.x = (ix_l * NPIX + iy_l) | ((ix_r * NPIX + iy_r) << 16);
      d.y = (ix_l * NPIX + iy_r) | ((ix_r * NPIX + iy_l) << 16);
      d.z = (unsigned)f2f16u(dxl * dyl) | ((unsigned)f2f16u(dxr * dyr) << 16);
      d.w = (unsigned)f2f16u(dxl * dyr) | ((unsigned)f2f16u(dxr * dyl) << 16);
      descL[n * 32 + m] = d;
    }
#undef LOADTAP
#undef WRITETILE
  }
  __syncthreads();                 // descL visible; Btile region dead
  __builtin_amdgcn_sched_barrier(0);

  // ======================= phase 2: gather GEMM =======================
  {
    int ow = t >> 6;
    char* A_lds0 = smem;                 // A_lds[buf] = smem + buf*8192
    const char* xb = (const char*)(xt + (size_t)b * NHW * 128);

    int m0 = t >> 4;            // row 0..15
    int m1 = m0 + 16;           // row 16..31
    int cb = (t & 15) * 16;     // byte col 0..240
    int ls0 = m0 * 256 + (cb ^ ((m0 & 7) << 4));
    int ls1 = m1 * 256 + (cb ^ ((m1 & 7) << 4));

    f32x4 acc[4][2];
#pragma unroll
    for (int of = 0; of < 4; ++of)
#pragma unroll
      for (int pf = 0; pf < 2; ++pf)
        acc[of][pf] = (f32x4){0.f, 0.f, 0.f, 0.f};

    u32x4 GX[4], GY[4];          // serialized liveness (never both live)
    uint2 zwX, zwY;
    uint4 dB0, dB1;

#define DLD(N, M) descL[(N) * 32 + (M)]

#define ISSUE_X()                                                              \
  {                                                                            \
    zwX.x = dB0.z; zwX.y = dB0.w;                                              \
    GX[0] = *reinterpret_cast<const u32x4*>(xb + (dB0.x & 0xffffu) * 256u + (unsigned)cb); \
    GX[1] = *reinterpret_cast<const u32x4*>(xb + (dB0.x >> 16)     * 256u + (unsigned)cb); \
    GX[2] = *reinterpret_cast<const u32x4*>(xb + (dB0.y & 0xffffu) * 256u + (unsigned)cb); \
    GX[3] = *reinterpret_cast<const u32x4*>(xb + (dB0.y >> 16)     * 256u + (unsigned)cb); \
  }

#define ISSUE_Y()                                                              \
  {                                                                            \
    zwY.x = dB1.z; zwY.y = dB1.w;                                              \
    GY[0] = *reinterpret_cast<const u32x4*>(xb + (dB1.x & 0xffffu) * 256u + (unsigned)cb); \
    GY[1] = *reinterpret_cast<const u32x4*>(xb + (dB1.x >> 16)     * 256u + (unsigned)cb); \
    GY[2] = *reinterpret_cast<const u32x4*>(xb + (dB1.y & 0xffffu) * 256u + (unsigned)cb); \
    GY[3] = *reinterpret_cast<const u32x4*>(xb + (dB1.y >> 16)     * 256u + (unsigned)cb); \
  }

#define COMB(G, ZW, LSO, WB)                                                   \
  {                                                                            \
    float w0 = f16u2f(ZW.x & 0xffffu), w1 = f16u2f(ZW.x >> 16);                \
    float w2 = f16u2f(ZW.y & 0xffffu), w3 = f16u2f(ZW.y >> 16);                \
    u32x4 pk;                                                                  \
    _Pragma("unroll")                                                          \
    for (int j = 0; j < 4; ++j){                                               \
      f32x2 a = w0 * bfp2f(G[0][j]) + w1 * bfp2f(G[1][j])                      \
              + w2 * bfp2f(G[2][j]) + w3 * bfp2f(G[3][j]);                     \
      pk[j] = pk_bf16(a.x, a.y);                                               \
    }                                                                          \
    *reinterpret_cast<u32x4*>((WB) + (LSO)) = pk;                              \
  }

#define MFMA_HALF(NN, KCA, KCB)                                                \
  {                                                                            \
    const char* ab = A_lds0 + ((NN) & 1) * 8192;                               \
    __builtin_amdgcn_s_setprio(1);                                             \
    _Pragma("unroll")                                                          \
    for (int kc = (KCA); kc <= (KCB); ++kc){                                   \
      bf16x8 bfrk[2];                                                          \
      _Pragma("unroll")                                                        \
      for (int pf = 0; pf < 2; ++pf){                                          \
        int row = pf * 16 + (lane & 15);                                       \
        bfrk[pf] = *reinterpret_cast<const bf16x8*>(                           \
            ab + row * 256 + ((kc * 64 + ((lane >> 4) & 3) * 16) ^ ((row & 7) << 4))); \
      }                                                                        \
      _Pragma("unroll")                                                        \
      for (int of = 0; of < 4; ++of){                                          \
        bf16x8 afr = *reinterpret_cast<const bf16x8*>(                         \
            &wf[((((NN) * 4 + kc) * 16) + ow * 4 + of) * 64 + lane]);          \
        _Pragma("unroll")                                                      \
        for (int pf = 0; pf < 2; ++pf)                                         \
          acc[of][pf] = __builtin_amdgcn_mfma_f32_16x16x32_bf16(afr, bfrk[pf], acc[of][pf], 0, 0, 0); \
      }                                                                        \
    }                                                                          \
    __builtin_amdgcn_s_setprio(0);                                             \
  }

// STEP(NN): issue X(data NN+1) | descL0(NN+2) | MFMA kc0-1 | COMB_X (GX dies)
//           | [sched fence] | issue Y(NN+1) | descL1(NN+2) | MFMA kc2-3
//           | COMB_Y | SOFT_BARRIER (no vmcnt drain -> next step's gathers
//           and this step's wf tails stay in flight).
#define STEP(NN)                                                               \
  {                                                                            \
    if ((NN) < 8){ ISSUE_X() }                                                 \
    if ((NN) < 7){ dB0 = DLD((NN) + 2, m0); }                                  \
    MFMA_HALF(NN, 0, 1)                                                        \
    if ((NN) < 8){                                                             \
      COMB(GX, zwX, ls0, A_lds0 + (((NN) + 1) & 1) * 8192)                     \
      __builtin_amdgcn_sched_barrier(0);                                       \
      ISSUE_Y()                                                                \
    }                                                                          \
    if ((NN) < 7){ dB1 = DLD((NN) + 2, m1); }                                  \
    MFMA_HALF(NN, 2, 3)                                                        \
    if ((NN) < 8){                                                             \
      COMB(GY, zwY, ls1, A_lds0 + (((NN) + 1) & 1) * 8192)                     \
    }                                                                          \
    SOFT_BARRIER();                                                            \
  }

    // prologue: data 0 -> buf0, one gather set live at a time
    dB0 = DLD(0, m0); dB1 = DLD(0, m1);
    ISSUE_X()
    COMB(GX, zwX, ls0, A_lds0)
    __builtin_amdgcn_sched_barrier(0);
    ISSUE_Y()
    COMB(GY, zwY, ls1, A_lds0)
    dB0 = DLD(1, m0); dB1 = DLD(1, m1);
    SOFT_BARRIER();

    STEP(0) STEP(1) STEP(2) STEP(3) STEP(4) STEP(5) STEP(6) STEP(7) STEP(8)

    // epilogue: +shift, fast SiLU, store
#pragma unroll
    for (int of = 0; of < 4; ++of)
#pragma unroll
      for (int pf = 0; pf < 2; ++pf){
        int pix = pixbase + pf * 16 + (lane & 15);
#pragma unroll
        for (int r = 0; r < 4; ++r){
          int o = ow * 64 + of * 16 + ((lane >> 4) & 3) * 4 + r;
          float v = acc[of][pf][r] + shift[o];
          out[(size_t)(b * 256 + o) * NHW + pix] = fast_silu(v);
        }
      }
#undef DLD
#undef ISSUE_X
#undef ISSUE_Y
#undef COMB
#undef MFMA_HALF
#undef STEP
  }
}

extern "C" void kernel_launch(void* const* d_in, const int* in_sizes, int n_in,
                              void* d_out, int out_size, void* d_ws, size_t ws_size,
                              hipStream_t stream){
  const float* x       = (const float*)d_in[0];
  const float* w_pconv = (const float*)d_in[1];
  const float* b_pconv = (const float*)d_in[2];
  const float* w_conv  = (const float*)d_in[3];
  const float* gamma   = (const float*)d_in[4];
  const float* beta    = (const float*)d_in[5];
  const float* mean    = (const float*)d_in[6];
  const float* var     = (const float*)d_in[7];
  const float* pn      = (const float*)d_in[8];

  char* ws = (char*)d_ws;
  unsigned short* xt  = (unsigned short*)(ws + 0);           // 13,107,200 B
  unsigned short* xtl = (unsigned short*)(ws + 13107200);    // 13,107,200 B
  // (desc region [26214400, 33587200) unused — kept for layout stability)
  uint4* wf           = (uint4*)(ws + 33587200);             //    589,824 B
  uint4* wpfH         = (uint4*)(ws + 34177024);             //     73,728 B
  uint4* wpfL         = (uint4*)(ws + 34250752);             //     73,728 B
  float* shift        = (float*)(ws + 34324480);             //      1,024 B
  float* out          = (float*)d_out;

  k_pre<<<981, 256, 0, stream>>>(x, w_conv, w_pconv, gamma, beta, mean, var,
                                 xt, xtl, wf, wpfH, wpfL, shift);
  k_fused<<<1600, 256, 0, stream>>>(xt, xtl, wpfH, wpfL, b_pconv, pn, wf, shift, out);
}